// Round 10
// baseline (566.303 us; speedup 1.0000x reference)
//
#include <hip/hip_runtime.h>
#include <hip/hip_fp16.h>
#include <math.h>

#define N_NODES 100000
#define N_EDGES 3200000
#define NHALF 50000
#define HIDDEN 32
#define K_TOP 35
#define NPG 100
#define N_GRAPHS 1000

#define BSHIFT 9
#define NLOC 512                    // nodes per bucket
#define NBUCK 196                   // ceil(100000/512)
#define CAP 17408                   // per-bucket capacity: mean 16384 + 8 sigma
#define NBB 2048                    // bin blocks
#define BIN_CHUNK 7                 // 2048*256*7 >= 3.2M

typedef float vfloat4 __attribute__((ext_vector_type(4)));  // native vec for nontemporal

// ---------------- CSR build: single-pass binning into padded buckets ----------------

__global__ void k_bin(const int* __restrict__ src, const int* __restrict__ dst,
                      int* __restrict__ bcnt, unsigned int* __restrict__ bdata) {
    __shared__ int h[NBUCK];
    __shared__ int lbase[NBUCK];
    __shared__ int lcur[NBUCK];
    int t = threadIdx.x;
    for (int i = t; i < NBUCK; i += 256) { h[i] = 0; lcur[i] = 0; }
    __syncthreads();
    int base = blockIdx.x * (256 * BIN_CHUNK);
    int ss[BIN_CHUNK], ds[BIN_CHUNK];
#pragma unroll
    for (int k = 0; k < BIN_CHUNK; k++) {
        int e = base + k * 256 + t;
        if (e < N_EDGES) {
            ss[k] = src[e];
            ds[k] = dst[e];
            atomicAdd(&h[ds[k] >> BSHIFT], 1);
        } else ds[k] = -1;
    }
    __syncthreads();
    for (int i = t; i < NBUCK; i += 256)
        lbase[i] = h[i] ? atomicAdd(&bcnt[i], h[i]) : 0;
    __syncthreads();
#pragma unroll
    for (int k = 0; k < BIN_CHUNK; k++) {
        int d = ds[k];
        if (d >= 0) {
            int bk = d >> BSHIFT;
            int pos = atomicAdd(&lcur[bk], 1);
            bdata[bk * CAP + lbase[bk] + pos] =
                ((unsigned int)ss[k] << BSHIFT) | (unsigned int)(d & (NLOC - 1));
        }
    }
}

// merged: per-bucket counts (+ src-half split counts) + within-bucket scan
// -> cnt/cntA/row_ptr/dis, then CSR fill with A-edges (src<NHALF) before B-edges.
__global__ void k_build(const unsigned int* __restrict__ bdata, const int* __restrict__ bcnt,
                        int* __restrict__ cnt, int* __restrict__ cntA,
                        int* __restrict__ row_ptr, float* __restrict__ dis,
                        int* __restrict__ csr) {
    __shared__ int h[NLOC];
    __shared__ int hA[NLOC];
    __shared__ int sd[NLOC];
    __shared__ int rp[NLOC];
    __shared__ int curA[NLOC];
    __shared__ int curB[NLOC];
    int b = blockIdx.x, t = threadIdx.x;   // 1024 threads
    if (t < NLOC) { h[t] = 0; hA[t] = 0; }
    __syncthreads();
    int r0 = b * CAP, r1 = r0 + bcnt[b];
    for (int i = r0 + t; i < r1; i += 1024) {
        unsigned int u = bdata[i];
        int loc = u & (NLOC - 1);
        atomicAdd(&h[loc], 1);
        if ((int)(u >> BSHIFT) < NHALF) atomicAdd(&hA[loc], 1);
    }
    __syncthreads();
    int v = (t < NLOC) ? h[t] : 0;
    if (t < NLOC) sd[t] = v;
    __syncthreads();
    for (int off = 1; off < NLOC; off <<= 1) {
        int x = (t >= off && t < NLOC) ? sd[t - off] : 0;
        __syncthreads();
        if (t < NLOC) sd[t] += x;
        __syncthreads();
    }
    if (t < NLOC) {
        int excl = sd[t] - v;
        int node = (b << BSHIFT) + t;
        rp[t] = r0 + excl;
        curA[t] = 0;
        curB[t] = 0;
        if (node < N_NODES) {
            cnt[node] = v;
            cntA[node] = hA[t];
            dis[node] = rsqrtf((float)(v + 1));
            row_ptr[node] = r0 + excl;
        }
    }
    __syncthreads();
    for (int i = r0 + t; i < r1; i += 1024) {
        unsigned int u = bdata[i];
        int loc = u & (NLOC - 1);
        int s = (int)(u >> BSHIFT);
        if (s < NHALF) {
            int pos = atomicAdd(&curA[loc], 1);
            csr[rp[loc] + pos] = s;
        } else {
            int pos = atomicAdd(&curB[loc], 1);
            csr[rp[loc] + hA[loc] + pos] = s;
        }
    }
}

// ---------------- GCN layer ----------------

// layer 0: hs[n] (fp16, 64B row) = dis[n] * (x @ w0); 2 nodes/thread halves LDS traffic
__global__ void k_mm0(const float* __restrict__ in, const float* __restrict__ w,
                      const float* __restrict__ dis, char* __restrict__ hs) {
    __shared__ float wl[128 * HIDDEN];
    int t = threadIdx.x;
    for (int i = t; i < 128 * HIDDEN; i += 256) wl[i] = w[i];
    __syncthreads();
    int n0 = blockIdx.x * 512 + t;
    int n1 = n0 + 256;
    bool has0 = n0 < N_NODES, has1 = n1 < N_NODES;
    int m0 = has0 ? n0 : 0, m1 = has1 ? n1 : 0;
    const float* r0p = in + (size_t)m0 * 128;
    const float* r1p = in + (size_t)m1 * 128;
    float acc0[HIDDEN], acc1[HIDDEN];
#pragma unroll
    for (int o = 0; o < HIDDEN; o++) { acc0[o] = 0.f; acc1[o] = 0.f; }
    for (int c4 = 0; c4 < 32; c4++) {
        float4 va = *(const float4*)(r0p + c4 * 4);
        float4 vb = *(const float4*)(r1p + c4 * 4);
        float xa[4] = {va.x, va.y, va.z, va.w};
        float xb[4] = {vb.x, vb.y, vb.z, vb.w};
#pragma unroll
        for (int k = 0; k < 4; k++) {
            const float* wr = &wl[(c4 * 4 + k) * HIDDEN];
#pragma unroll
            for (int o = 0; o < HIDDEN; o++) {
                float wv = wr[o];
                acc0[o] += xa[k] * wv;
                acc1[o] += xb[k] * wv;
            }
        }
    }
    if (has0) {
        float d = dis[m0];
        float4* hr = (float4*)(hs + (size_t)m0 * 64);
#pragma unroll
        for (int qq = 0; qq < 4; qq++) {
            __half2 p[4];
#pragma unroll
            for (int k = 0; k < 4; k++)
                p[k] = __floats2half2_rn(acc0[8 * qq + 2 * k] * d, acc0[8 * qq + 2 * k + 1] * d);
            hr[qq] = *(float4*)p;
        }
    }
    if (has1) {
        float d = dis[m1];
        float4* hr = (float4*)(hs + (size_t)m1 * 64);
#pragma unroll
        for (int qq = 0; qq < 4; qq++) {
            __half2 p[4];
#pragma unroll
            for (int k = 0; k < 4; k++)
                p[k] = __floats2half2_rn(acc1[8 * qq + 2 * k] * d, acc1[8 * qq + 2 * k + 1] * d);
            hr[qq] = *(float4*)p;
        }
    }
}

// pass A: gather ONLY Lo-half src rows (3.2MB L2-resident table) for edges [0,mA),
// write raw fp32 partial sums into the node's feat slot. half-wave per node.
__global__ void k_aggA(const float4* __restrict__ hs4,
                       const int* __restrict__ row_ptr, const int* __restrict__ cntA,
                       const int* __restrict__ csr_src,
                       float* __restrict__ feat, int col_off) {
    int tt = threadIdx.x;
    int n = (blockIdx.x * 256 + tt) >> 5;
    int c = tt & 31;
    int r = c & 3;
    int ph = c >> 2;
    int start = row_ptr[n];
    int mA = cntA[n];
    float aA[8] = {0, 0, 0, 0, 0, 0, 0, 0};
    float aB[8] = {0, 0, 0, 0, 0, 0, 0, 0};
    for (int base = 0; base < mA; base += 32) {
        int e = base + c;
        int ec = (e < mA) ? e : mA - 1;                  // clamp: always a valid Lo idx
        int idx = __builtin_nontemporal_load(&csr_src[start + ec]);
        int id0 = __shfl(idx, ph, 32);
        int id1 = __shfl(idx, 8 + ph, 32);
        int id2 = __shfl(idx, 16 + ph, 32);
        int id3 = __shfl(idx, 24 + ph, 32);
        bool v0 = base + ph < mA;
        bool v1 = base + 8 + ph < mA;
        bool v2 = base + 16 + ph < mA;
        bool v3 = base + 24 + ph < mA;
        float4 g0 = hs4[(size_t)id0 * 4 + r];
        float4 g1 = hs4[(size_t)id1 * 4 + r];
        float4 g2 = hs4[(size_t)id2 * 4 + r];
        float4 g3 = hs4[(size_t)id3 * 4 + r];
        const __half2* h0 = (const __half2*)&g0;
        const __half2* h1 = (const __half2*)&g1;
        const __half2* h2 = (const __half2*)&g2;
        const __half2* h3 = (const __half2*)&g3;
        float2 f;
        if (v0) {
            f = __half22float2(h0[0]); aA[0] += f.x; aA[1] += f.y;
            f = __half22float2(h0[1]); aA[2] += f.x; aA[3] += f.y;
            f = __half22float2(h0[2]); aA[4] += f.x; aA[5] += f.y;
            f = __half22float2(h0[3]); aA[6] += f.x; aA[7] += f.y;
        }
        if (v1) {
            f = __half22float2(h1[0]); aB[0] += f.x; aB[1] += f.y;
            f = __half22float2(h1[1]); aB[2] += f.x; aB[3] += f.y;
            f = __half22float2(h1[2]); aB[4] += f.x; aB[5] += f.y;
            f = __half22float2(h1[3]); aB[6] += f.x; aB[7] += f.y;
        }
        if (v2) {
            f = __half22float2(h2[0]); aA[0] += f.x; aA[1] += f.y;
            f = __half22float2(h2[1]); aA[2] += f.x; aA[3] += f.y;
            f = __half22float2(h2[2]); aA[4] += f.x; aA[5] += f.y;
            f = __half22float2(h2[3]); aA[6] += f.x; aA[7] += f.y;
        }
        if (v3) {
            f = __half22float2(h3[0]); aB[0] += f.x; aB[1] += f.y;
            f = __half22float2(h3[1]); aB[2] += f.x; aB[3] += f.y;
            f = __half22float2(h3[2]); aB[4] += f.x; aB[5] += f.y;
            f = __half22float2(h3[3]); aB[6] += f.x; aB[7] += f.y;
        }
    }
    float s[8];
#pragma unroll
    for (int k = 0; k < 8; k++) {
        float v = aA[k] + aB[k];
        v += __shfl_xor(v, 4);
        v += __shfl_xor(v, 8);
        v += __shfl_xor(v, 16);
        s[k] = v;
    }
    if (c < 4) {
        float* fr = feat + (size_t)n * 128 + col_off + 8 * c;
        vfloat4 o0 = {s[0], s[1], s[2], s[3]};
        vfloat4 o1 = {s[4], s[5], s[6], s[7]};
        __builtin_nontemporal_store(o0, (vfloat4*)fr);
        __builtin_nontemporal_store(o1, (vfloat4*)(fr + 4));
    }
}

// pass B: gather Hi-half rows for edges [mA,m), add fp32 partial from feat,
// tanh + final feat write + fused next-layer matvec (LDS tv, R7 structure).
__global__ void k_aggB(const float4* __restrict__ hs4, const float* __restrict__ dis,
                       const int* __restrict__ row_ptr, const int* __restrict__ cnt,
                       const int* __restrict__ cntA, const int* __restrict__ csr_src,
                       const float* __restrict__ bias,
                       float* __restrict__ feat, int col_off,
                       const float* __restrict__ wnext, char* __restrict__ hsn) {
    __shared__ float wl[32 * 33];
    __shared__ float tv[8][36];
    int tt = threadIdx.x;
    if (wnext) {
        for (int i = tt; i < 1024; i += 256)
            wl[(i >> 5) * 33 + (i & 31)] = wnext[i];
    }
    __syncthreads();
    int n = (blockIdx.x * 256 + tt) >> 5;
    int c = tt & 31;
    int r = c & 3;
    int ph = c >> 2;
    int slot = tt >> 5;
    int start = row_ptr[n];
    int m = cnt[n];
    int mA = cntA[n];
    float d = dis[n];
    float aA[8] = {0, 0, 0, 0, 0, 0, 0, 0};
    float aB[8] = {0, 0, 0, 0, 0, 0, 0, 0};
    for (int base = mA; base < m; base += 32) {
        int e = base + c;
        int ec = (e < m) ? e : m - 1;                    // clamp: always a valid Hi idx
        int idx = __builtin_nontemporal_load(&csr_src[start + ec]);
        int id0 = __shfl(idx, ph, 32);
        int id1 = __shfl(idx, 8 + ph, 32);
        int id2 = __shfl(idx, 16 + ph, 32);
        int id3 = __shfl(idx, 24 + ph, 32);
        bool v0 = base + ph < m;
        bool v1 = base + 8 + ph < m;
        bool v2 = base + 16 + ph < m;
        bool v3 = base + 24 + ph < m;
        float4 g0 = hs4[(size_t)id0 * 4 + r];
        float4 g1 = hs4[(size_t)id1 * 4 + r];
        float4 g2 = hs4[(size_t)id2 * 4 + r];
        float4 g3 = hs4[(size_t)id3 * 4 + r];
        const __half2* h0 = (const __half2*)&g0;
        const __half2* h1 = (const __half2*)&g1;
        const __half2* h2 = (const __half2*)&g2;
        const __half2* h3 = (const __half2*)&g3;
        float2 f;
        if (v0) {
            f = __half22float2(h0[0]); aA[0] += f.x; aA[1] += f.y;
            f = __half22float2(h0[1]); aA[2] += f.x; aA[3] += f.y;
            f = __half22float2(h0[2]); aA[4] += f.x; aA[5] += f.y;
            f = __half22float2(h0[3]); aA[6] += f.x; aA[7] += f.y;
        }
        if (v1) {
            f = __half22float2(h1[0]); aB[0] += f.x; aB[1] += f.y;
            f = __half22float2(h1[1]); aB[2] += f.x; aB[3] += f.y;
            f = __half22float2(h1[2]); aB[4] += f.x; aB[5] += f.y;
            f = __half22float2(h1[3]); aB[6] += f.x; aB[7] += f.y;
        }
        if (v2) {
            f = __half22float2(h2[0]); aA[0] += f.x; aA[1] += f.y;
            f = __half22float2(h2[1]); aA[2] += f.x; aA[3] += f.y;
            f = __half22float2(h2[2]); aA[4] += f.x; aA[5] += f.y;
            f = __half22float2(h2[3]); aA[6] += f.x; aA[7] += f.y;
        }
        if (v3) {
            f = __half22float2(h3[0]); aB[0] += f.x; aB[1] += f.y;
            f = __half22float2(h3[1]); aB[2] += f.x; aB[3] += f.y;
            f = __half22float2(h3[2]); aB[4] += f.x; aB[5] += f.y;
            f = __half22float2(h3[3]); aB[6] += f.x; aB[7] += f.y;
        }
    }
    float s[8];
#pragma unroll
    for (int k = 0; k < 8; k++) {
        float v = aA[k] + aB[k];
        v += __shfl_xor(v, 4);
        v += __shfl_xor(v, 8);
        v += __shfl_xor(v, 16);
        s[k] = v;
    }
    // epilogue: lanes c<4 handle channels 8c..8c+7
    if (c < 4) {
        const float* fr = feat + (size_t)n * 128 + col_off + 8 * c;
        float4 p0 = *(const float4*)fr;          // fp32 partial from pass A
        float4 p1 = *(const float4*)(fr + 4);
        s[0] += p0.x; s[1] += p0.y; s[2] += p0.z; s[3] += p0.w;
        s[4] += p1.x; s[5] += p1.y; s[6] += p1.z; s[7] += p1.w;
        float4 sv = hs4[(size_t)n * 4 + r];
        const __half2* sh = (const __half2*)&sv;
        float ov[8];
#pragma unroll
        for (int k = 0; k < 4; k++) {
            float2 f = __half22float2(sh[k]);
            ov[2 * k]     = tanhf(d * (s[2 * k]     + f.x) + bias[8 * c + 2 * k]);
            ov[2 * k + 1] = tanhf(d * (s[2 * k + 1] + f.y) + bias[8 * c + 2 * k + 1]);
        }
        float* fw = feat + (size_t)n * 128 + col_off + 8 * c;
        vfloat4 o0 = {ov[0], ov[1], ov[2], ov[3]};
        vfloat4 o1 = {ov[4], ov[5], ov[6], ov[7]};
        __builtin_nontemporal_store(o0, (vfloat4*)fw);
        __builtin_nontemporal_store(o1, (vfloat4*)(fw + 4));
        if (wnext) {
            *(float4*)&tv[slot][8 * c]     = make_float4(ov[0], ov[1], ov[2], ov[3]);
            *(float4*)&tv[slot][8 * c + 4] = make_float4(ov[4], ov[5], ov[6], ov[7]);
        }
    }
    if (wnext) {
        __builtin_amdgcn_wave_barrier();   // tv writes before reads (same wave)
        float o = 0.f;
#pragma unroll 8
        for (int k = 0; k < 32; k++)
            o += tv[slot][k] * wl[k * 33 + c];
        o *= d;
        float oh = __shfl_xor(o, 1);
        if ((c & 1) == 0) {
            __half2 pck = __floats2half2_rn(o, oh);
            *(__half2*)(hsn + (size_t)n * 64 + (size_t)c * 2) = pck;
        }
    }
}

// ---------------- sort-pool + head (one block per graph) ----------------

__global__ void __launch_bounds__(256, 4)
k_head(const float* __restrict__ feat,
       const float* __restrict__ c1w, const float* __restrict__ c1b,
       const float* __restrict__ c2w, const float* __restrict__ c2b,
       const float* __restrict__ f1w, const float* __restrict__ f1b,
       const float* __restrict__ f2w, const float* __restrict__ f2b,
       float* __restrict__ out) {
    __shared__ float vals[NPG];
    __shared__ int sel[K_TOP];
    __shared__ float tk[K_TOP * 132];
    __shared__ float wl1[16 * 129];
    __shared__ float y1[16][36];
    __shared__ float y2[16][17];
    __shared__ float y3[416];
    __shared__ float y4[128];
    __shared__ float r2[128];
    int g = blockIdx.x, t = threadIdx.x;
    const float* fg = feat + (size_t)g * NPG * 128;

    for (int i = t; i < 2048; i += 256)
        wl1[(i >> 7) * 129 + (i & 127)] = c1w[i];
    if (t < NPG) vals[t] = fg[t * 128 + 127];
    __syncthreads();
    // stable descending rank (matches stable argsort(-v))
    if (t < NPG) {
        float v = vals[t];
        int r = 0;
        for (int j = 0; j < NPG; j++) {
            float u = vals[j];
            r += (u > v) || (u == v && j < t);
        }
        if (r < K_TOP) sel[r] = t;
    }
    __syncthreads();
    for (int i = t; i < K_TOP * 32; i += 256) {
        int k = i >> 5, c4 = i & 31;
        *(float4*)&tk[k * 132 + 4 * c4] = *(const float4*)&fg[sel[k] * 128 + 4 * c4];
    }
    __syncthreads();
    // conv1 (1x1), weights from LDS
    for (int i = t; i < 16 * K_TOP; i += 256) {
        int o = i & 15, k = i >> 4;
        float s = c1b[o];
        const float* wr = &wl1[o * 129];
        const float* xr = &tk[k * 132];
#pragma unroll 8
        for (int c = 0; c < 128; c++) s += wr[c] * xr[c];
        y1[o][k] = fmaxf(s, 0.f);
    }
    __syncthreads();
    // maxpool1d(2): 35 -> 17
    for (int i = t; i < 16 * 17; i += 256) {
        int o = i & 15, l = i >> 4;
        y2[o][l] = fmaxf(y1[o][2 * l], y1[o][2 * l + 1]);
    }
    __syncthreads();
    // conv2 (k=5, VALID): [16,17] -> [32,13]
    for (int idx = t; idx < 32 * 13; idx += 256) {
        int o2 = idx / 13, ttp = idx - o2 * 13;
        float s = c2b[o2];
        const float* wr = c2w + o2 * 80;
#pragma unroll
        for (int i = 0; i < 16; i++)
#pragma unroll
            for (int j = 0; j < 5; j++) s += wr[i * 5 + j] * y2[i][ttp + j];
        y3[idx] = fmaxf(s, 0.f);
    }
    __syncthreads();
    // fc1: 416 -> 128, 2 threads per output, float4 weight loads
    {
        int o = t >> 1, h = t & 1;
        const float4* wr4 = (const float4*)(f1w + o * 416) + h * 52;
        const float* yb = y3 + h * 208;
        float s = 0.f;
#pragma unroll 4
        for (int i = 0; i < 52; i++) {
            float4 w4 = wr4[i];
            s += w4.x * yb[4 * i] + w4.y * yb[4 * i + 1] +
                 w4.z * yb[4 * i + 2] + w4.w * yb[4 * i + 3];
        }
        s += __shfl_xor(s, 1);
        if (h == 0) y4[o] = fmaxf(s + f1b[o], 0.f);
    }
    __syncthreads();
    if (t < 128) r2[t] = f2w[t] * y4[t];
    __syncthreads();
    for (int off = 64; off > 0; off >>= 1) {
        if (t < off) r2[t] += r2[t + off];
        __syncthreads();
    }
    if (t == 0) out[g] = 1.0f / (1.0f + expf(-(r2[0] + f2b[0])));
}

// ---------------- launch ----------------

static inline size_t alignup(size_t x) { return (x + 255) & ~(size_t)255; }

extern "C" void kernel_launch(void* const* d_in, const int* in_sizes, int n_in,
                              void* d_out, int out_size, void* d_ws, size_t ws_size,
                              hipStream_t stream) {
    const float* x    = (const float*)d_in[0];
    const int*   ei   = (const int*)d_in[1];
    const int*   srcp = ei;
    const int*   dstp = ei + N_EDGES;
    const float* w0 = (const float*)d_in[3];
    const float* b0 = (const float*)d_in[4];
    const float* w1 = (const float*)d_in[5];
    const float* b1 = (const float*)d_in[6];
    const float* w2 = (const float*)d_in[7];
    const float* b2 = (const float*)d_in[8];
    const float* w3 = (const float*)d_in[9];
    const float* b3 = (const float*)d_in[10];
    const float* c1w = (const float*)d_in[11];
    const float* c1b = (const float*)d_in[12];
    const float* c2w = (const float*)d_in[13];
    const float* c2b = (const float*)d_in[14];
    const float* f1w = (const float*)d_in[15];
    const float* f1b = (const float*)d_in[16];
    const float* f2w = (const float*)d_in[17];
    const float* f2b = (const float*)d_in[18];
    float* out = (float*)d_out;

    char* p = (char*)d_ws;
    int* cnt     = (int*)p; p += alignup(sizeof(int) * N_NODES);
    int* cntA    = (int*)p; p += alignup(sizeof(int) * N_NODES);
    int* row_ptr = (int*)p; p += alignup(sizeof(int) * N_NODES);
    float* dis   = (float*)p; p += alignup(sizeof(float) * N_NODES);
    int* bcnt    = (int*)p; p += alignup(sizeof(int) * NBUCK);
    int* csr     = (int*)p; p += alignup(sizeof(int) * (size_t)NBUCK * CAP);
    // union region: bdata (dead after k_build) aliases the two fp16 hs buffers
    char* U = p;
    unsigned int* bdata = (unsigned int*)U;
    char* hsA = U;                                        // 6.4 MB fp16
    char* hsB = U + alignup((size_t)N_NODES * 64);        // 6.4 MB fp16
    size_t usz = alignup(sizeof(unsigned int) * (size_t)NBUCK * CAP); // 13.65 MB
    float* feat = (float*)(U + usz);

    const int NB_M = (N_NODES + 511) / 512;        // 196 (2 nodes/thread)
    const int NB_A = (N_NODES * 32) / 256;         // 12500 (exact)

    hipMemsetAsync(bcnt, 0, sizeof(int) * NBUCK, stream);
    k_bin<<<NBB, 256, 0, stream>>>(srcp, dstp, bcnt, bdata);
    k_build<<<NBUCK, 1024, 0, stream>>>(bdata, bcnt, cnt, cntA, row_ptr, dis, csr);

    k_mm0<<<NB_M, 256, 0, stream>>>(x, w0, dis, hsA);

    const float* ws[4] = {w1, w2, w3, nullptr};
    const float* bs[4] = {b0, b1, b2, b3};
    char* hcur = hsA;
    char* hnxt = hsB;
    for (int l = 0; l < 4; l++) {
        k_aggA<<<NB_A, 256, 0, stream>>>((const float4*)hcur, row_ptr, cntA, csr,
                                         feat, 32 * l);
        k_aggB<<<NB_A, 256, 0, stream>>>((const float4*)hcur, dis, row_ptr, cnt, cntA,
                                         csr, bs[l], feat, 32 * l, ws[l],
                                         ws[l] ? hnxt : (char*)nullptr);
        char* tmp = hcur; hcur = hnxt; hnxt = tmp;
    }

    k_head<<<N_GRAPHS, 256, 0, stream>>>(feat, c1w, c1b, c2w, c2b,
                                         f1w, f1b, f2w, f2b, out);
}

// Round 11
// 488.819 us; speedup vs baseline: 1.1585x; 1.1585x over previous
//
#include <hip/hip_runtime.h>
#include <hip/hip_fp16.h>
#include <math.h>

#define N_NODES 100000
#define N_EDGES 3200000
#define HIDDEN 32
#define K_TOP 35
#define NPG 100
#define N_GRAPHS 1000

#define BSHIFT 9
#define NLOC 512                    // nodes per bucket
#define NBUCK 196                   // ceil(100000/512)
#define CAP 17408                   // per-bucket capacity: mean 16384 + 8 sigma
#define NBB 2048                    // bin blocks
#define BIN_CHUNK 7                 // 2048*256*7 >= 3.2M

typedef float vfloat4 __attribute__((ext_vector_type(4)));  // native vec for nontemporal

// ---------------- CSR build: single-pass binning into padded buckets ----------------

__global__ void k_bin(const int* __restrict__ src, const int* __restrict__ dst,
                      int* __restrict__ bcnt, unsigned int* __restrict__ bdata) {
    __shared__ int h[NBUCK];
    __shared__ int lbase[NBUCK];
    __shared__ int lcur[NBUCK];
    int t = threadIdx.x;
    for (int i = t; i < NBUCK; i += 256) { h[i] = 0; lcur[i] = 0; }
    __syncthreads();
    int base = blockIdx.x * (256 * BIN_CHUNK);
    int ss[BIN_CHUNK], ds[BIN_CHUNK];
#pragma unroll
    for (int k = 0; k < BIN_CHUNK; k++) {
        int e = base + k * 256 + t;
        if (e < N_EDGES) {
            ss[k] = src[e];
            ds[k] = dst[e];
            atomicAdd(&h[ds[k] >> BSHIFT], 1);
        } else ds[k] = -1;
    }
    __syncthreads();
    for (int i = t; i < NBUCK; i += 256)
        lbase[i] = h[i] ? atomicAdd(&bcnt[i], h[i]) : 0;
    __syncthreads();
#pragma unroll
    for (int k = 0; k < BIN_CHUNK; k++) {
        int d = ds[k];
        if (d >= 0) {
            int bk = d >> BSHIFT;
            int pos = atomicAdd(&lcur[bk], 1);
            bdata[bk * CAP + lbase[bk] + pos] =
                ((unsigned int)ss[k] << BSHIFT) | (unsigned int)(d & (NLOC - 1));
        }
    }
}

// merged: per-bucket counts + within-bucket scan -> cnt/row_ptr/dis, then CSR fill.
__global__ void k_build(const unsigned int* __restrict__ bdata, const int* __restrict__ bcnt,
                        int* __restrict__ cnt, int* __restrict__ row_ptr,
                        float* __restrict__ dis, int* __restrict__ csr) {
    __shared__ int h[NLOC];
    __shared__ int sd[NLOC];
    __shared__ int rp[NLOC];
    __shared__ int cur[NLOC];
    int b = blockIdx.x, t = threadIdx.x;   // 1024 threads
    if (t < NLOC) h[t] = 0;
    __syncthreads();
    int r0 = b * CAP, r1 = r0 + bcnt[b];
    for (int i = r0 + t; i < r1; i += 1024)
        atomicAdd(&h[bdata[i] & (NLOC - 1)], 1);
    __syncthreads();
    int v = (t < NLOC) ? h[t] : 0;
    if (t < NLOC) sd[t] = v;
    __syncthreads();
    for (int off = 1; off < NLOC; off <<= 1) {
        int x = (t >= off && t < NLOC) ? sd[t - off] : 0;
        __syncthreads();
        if (t < NLOC) sd[t] += x;
        __syncthreads();
    }
    if (t < NLOC) {
        int excl = sd[t] - v;
        int node = (b << BSHIFT) + t;
        rp[t] = r0 + excl;
        cur[t] = 0;
        if (node < N_NODES) {
            cnt[node] = v;
            dis[node] = rsqrtf((float)(v + 1));
            row_ptr[node] = r0 + excl;
        }
    }
    __syncthreads();
    for (int i = r0 + t; i < r1; i += 1024) {
        unsigned int u = bdata[i];
        int loc = u & (NLOC - 1);
        int pos = atomicAdd(&cur[loc], 1);
        csr[rp[loc] + pos] = (int)(u >> BSHIFT);
    }
}

// ---------------- GCN layer ----------------

// layer 0: hs[n] (fp16, 64B row) = dis[n] * (x @ w0); 2 nodes/thread halves LDS traffic
__global__ void k_mm0(const float* __restrict__ in, const float* __restrict__ w,
                      const float* __restrict__ dis, char* __restrict__ hs) {
    __shared__ float wl[128 * HIDDEN];
    int t = threadIdx.x;
    for (int i = t; i < 128 * HIDDEN; i += 256) wl[i] = w[i];
    __syncthreads();
    int n0 = blockIdx.x * 512 + t;
    int n1 = n0 + 256;
    bool has0 = n0 < N_NODES, has1 = n1 < N_NODES;
    int m0 = has0 ? n0 : 0, m1 = has1 ? n1 : 0;
    const float* r0p = in + (size_t)m0 * 128;
    const float* r1p = in + (size_t)m1 * 128;
    float acc0[HIDDEN], acc1[HIDDEN];
#pragma unroll
    for (int o = 0; o < HIDDEN; o++) { acc0[o] = 0.f; acc1[o] = 0.f; }
    for (int c4 = 0; c4 < 32; c4++) {
        float4 va = *(const float4*)(r0p + c4 * 4);
        float4 vb = *(const float4*)(r1p + c4 * 4);
        float xa[4] = {va.x, va.y, va.z, va.w};
        float xb[4] = {vb.x, vb.y, vb.z, vb.w};
#pragma unroll
        for (int k = 0; k < 4; k++) {
            const float* wr = &wl[(c4 * 4 + k) * HIDDEN];
#pragma unroll
            for (int o = 0; o < HIDDEN; o++) {
                float wv = wr[o];
                acc0[o] += xa[k] * wv;
                acc1[o] += xb[k] * wv;
            }
        }
    }
    if (has0) {
        float d = dis[m0];
        float4* hr = (float4*)(hs + (size_t)m0 * 64);
#pragma unroll
        for (int qq = 0; qq < 4; qq++) {
            __half2 p[4];
#pragma unroll
            for (int k = 0; k < 4; k++)
                p[k] = __floats2half2_rn(acc0[8 * qq + 2 * k] * d, acc0[8 * qq + 2 * k + 1] * d);
            hr[qq] = *(float4*)p;
        }
    }
    if (has1) {
        float d = dis[m1];
        float4* hr = (float4*)(hs + (size_t)m1 * 64);
#pragma unroll
        for (int qq = 0; qq < 4; qq++) {
            __half2 p[4];
#pragma unroll
            for (int k = 0; k < 4; k++)
                p[k] = __floats2half2_rn(acc1[8 * qq + 2 * k] * d, acc1[8 * qq + 2 * k + 1] * d);
            hr[qq] = *(float4*)p;
        }
    }
}

// fused: aggregate (fp16 gather, chunk-shuffle, fp32 accumulate) + tanh + feat write
// + next-layer matvec (LDS tv). half-wave per node; full 32-edge chunks issue 4
// unconditional gathers/lane (no validity logic); tail issues only ceil(rem/8) steps.
__global__ void k_agg(const float4* __restrict__ hs4, const float* __restrict__ dis,
                      const int* __restrict__ row_ptr, const int* __restrict__ cnt,
                      const int* __restrict__ csr_src, const float* __restrict__ bias,
                      float* __restrict__ feat, int col_off,
                      const float* __restrict__ wnext, char* __restrict__ hsn) {
    __shared__ float wl[32 * 33];
    __shared__ float tv[8][36];
    int tt = threadIdx.x;
    if (wnext) {
        for (int i = tt; i < 1024; i += 256)
            wl[(i >> 5) * 33 + (i & 31)] = wnext[i];
    }
    __syncthreads();
    int n = (blockIdx.x * 256 + tt) >> 5;   // grid covers exactly N_NODES*32 lanes
    int c = tt & 31;
    int r = c & 3;       // 16B quad within 64B row
    int ph = c >> 2;     // edge phase (0..7)
    int slot = tt >> 5;
    int start = row_ptr[n];
    int m = cnt[n];
    float d = dis[n];
    float aA[8] = {0, 0, 0, 0, 0, 0, 0, 0};
    float aB[8] = {0, 0, 0, 0, 0, 0, 0, 0};

    int base = 0;
    // ---- full chunks: 32 valid edges, zero validity logic ----
    for (; base + 32 <= m; base += 32) {
        int idx = csr_src[start + base + c];
        int id0 = __shfl(idx, ph, 32);
        int id1 = __shfl(idx, 8 + ph, 32);
        int id2 = __shfl(idx, 16 + ph, 32);
        int id3 = __shfl(idx, 24 + ph, 32);
        float4 g0 = hs4[(size_t)id0 * 4 + r];
        float4 g1 = hs4[(size_t)id1 * 4 + r];
        float4 g2 = hs4[(size_t)id2 * 4 + r];
        float4 g3 = hs4[(size_t)id3 * 4 + r];
        const __half2* h0 = (const __half2*)&g0;
        const __half2* h1 = (const __half2*)&g1;
        const __half2* h2 = (const __half2*)&g2;
        const __half2* h3 = (const __half2*)&g3;
        float2 f;
        f = __half22float2(h0[0]); aA[0] += f.x; aA[1] += f.y;
        f = __half22float2(h0[1]); aA[2] += f.x; aA[3] += f.y;
        f = __half22float2(h0[2]); aA[4] += f.x; aA[5] += f.y;
        f = __half22float2(h0[3]); aA[6] += f.x; aA[7] += f.y;
        f = __half22float2(h1[0]); aB[0] += f.x; aB[1] += f.y;
        f = __half22float2(h1[1]); aB[2] += f.x; aB[3] += f.y;
        f = __half22float2(h1[2]); aB[4] += f.x; aB[5] += f.y;
        f = __half22float2(h1[3]); aB[6] += f.x; aB[7] += f.y;
        f = __half22float2(h2[0]); aA[0] += f.x; aA[1] += f.y;
        f = __half22float2(h2[1]); aA[2] += f.x; aA[3] += f.y;
        f = __half22float2(h2[2]); aA[4] += f.x; aA[5] += f.y;
        f = __half22float2(h2[3]); aA[6] += f.x; aA[7] += f.y;
        f = __half22float2(h3[0]); aB[0] += f.x; aB[1] += f.y;
        f = __half22float2(h3[1]); aB[2] += f.x; aB[3] += f.y;
        f = __half22float2(h3[2]); aB[4] += f.x; aB[5] += f.y;
        f = __half22float2(h3[3]); aB[6] += f.x; aB[7] += f.y;
    }
    // ---- tail: rem in [0,32); issue only ceil(rem/8) gather steps ----
    int rem = m - base;
    if (rem > 0) {
        int cc = (c < rem) ? c : rem - 1;
        int idx = csr_src[start + base + cc];
        int id0 = __shfl(idx, ph, 32);
        int id1 = __shfl(idx, 8 + ph, 32);
        int id2 = __shfl(idx, 16 + ph, 32);
        int id3 = __shfl(idx, 24 + ph, 32);
        float2 f;
        {   // step 0 (always: rem >= 1)
            bool v = ph < rem;
            float4 g = hs4[(size_t)(v ? id0 : n) * 4 + r];
            const __half2* h = (const __half2*)&g;
            if (v) {
                f = __half22float2(h[0]); aA[0] += f.x; aA[1] += f.y;
                f = __half22float2(h[1]); aA[2] += f.x; aA[3] += f.y;
                f = __half22float2(h[2]); aA[4] += f.x; aA[5] += f.y;
                f = __half22float2(h[3]); aA[6] += f.x; aA[7] += f.y;
            }
        }
        if (rem > 8) {
            bool v = 8 + ph < rem;
            float4 g = hs4[(size_t)(v ? id1 : n) * 4 + r];
            const __half2* h = (const __half2*)&g;
            if (v) {
                f = __half22float2(h[0]); aB[0] += f.x; aB[1] += f.y;
                f = __half22float2(h[1]); aB[2] += f.x; aB[3] += f.y;
                f = __half22float2(h[2]); aB[4] += f.x; aB[5] += f.y;
                f = __half22float2(h[3]); aB[6] += f.x; aB[7] += f.y;
            }
        }
        if (rem > 16) {
            bool v = 16 + ph < rem;
            float4 g = hs4[(size_t)(v ? id2 : n) * 4 + r];
            const __half2* h = (const __half2*)&g;
            if (v) {
                f = __half22float2(h[0]); aA[0] += f.x; aA[1] += f.y;
                f = __half22float2(h[1]); aA[2] += f.x; aA[3] += f.y;
                f = __half22float2(h[2]); aA[4] += f.x; aA[5] += f.y;
                f = __half22float2(h[3]); aA[6] += f.x; aA[7] += f.y;
            }
        }
        if (rem > 24) {
            bool v = 24 + ph < rem;
            float4 g = hs4[(size_t)(v ? id3 : n) * 4 + r];
            const __half2* h = (const __half2*)&g;
            if (v) {
                f = __half22float2(h[0]); aB[0] += f.x; aB[1] += f.y;
                f = __half22float2(h[1]); aB[2] += f.x; aB[3] += f.y;
                f = __half22float2(h[2]); aB[4] += f.x; aB[5] += f.y;
                f = __half22float2(h[3]); aB[6] += f.x; aB[7] += f.y;
            }
        }
    }
    float s[8];
#pragma unroll
    for (int k = 0; k < 8; k++) {
        float v = aA[k] + aB[k];
        v += __shfl_xor(v, 4);
        v += __shfl_xor(v, 8);
        v += __shfl_xor(v, 16);
        s[k] = v;   // lanes with same r hold full sums for channels 8r..8r+7
    }
    // epilogue: lanes c<4 handle channels 8c..8c+7
    if (c < 4) {
        float4 sv = hs4[(size_t)n * 4 + r];
        const __half2* sh = (const __half2*)&sv;
        float ov[8];
#pragma unroll
        for (int k = 0; k < 4; k++) {
            float2 f = __half22float2(sh[k]);
            ov[2 * k]     = tanhf(d * (s[2 * k]     + f.x) + bias[8 * c + 2 * k]);
            ov[2 * k + 1] = tanhf(d * (s[2 * k + 1] + f.y) + bias[8 * c + 2 * k + 1]);
        }
        float* fr = feat + (size_t)n * 128 + col_off + 8 * c;
        vfloat4 o0 = {ov[0], ov[1], ov[2], ov[3]};
        vfloat4 o1 = {ov[4], ov[5], ov[6], ov[7]};
        __builtin_nontemporal_store(o0, (vfloat4*)fr);
        __builtin_nontemporal_store(o1, (vfloat4*)(fr + 4));
        if (wnext) {
            *(float4*)&tv[slot][8 * c]     = make_float4(ov[0], ov[1], ov[2], ov[3]);
            *(float4*)&tv[slot][8 * c + 4] = make_float4(ov[4], ov[5], ov[6], ov[7]);
        }
    }
    if (wnext) {
        __builtin_amdgcn_wave_barrier();   // tv writes before reads (same wave)
        float o = 0.f;
#pragma unroll 8
        for (int k = 0; k < 32; k++)
            o += tv[slot][k] * wl[k * 33 + c];
        o *= d;
        float oh = __shfl_xor(o, 1);
        if ((c & 1) == 0) {
            __half2 pck = __floats2half2_rn(o, oh);
            *(__half2*)(hsn + (size_t)n * 64 + (size_t)c * 2) = pck;
        }
    }
}

// ---------------- sort-pool + head (one block per graph) ----------------

__global__ void __launch_bounds__(256, 4)
k_head(const float* __restrict__ feat,
       const float* __restrict__ c1w, const float* __restrict__ c1b,
       const float* __restrict__ c2w, const float* __restrict__ c2b,
       const float* __restrict__ f1w, const float* __restrict__ f1b,
       const float* __restrict__ f2w, const float* __restrict__ f2b,
       float* __restrict__ out) {
    __shared__ float vals[NPG];
    __shared__ int sel[K_TOP];
    __shared__ float tk[K_TOP * 132];
    __shared__ float wl1[16 * 129];
    __shared__ float y1[16][36];
    __shared__ float y2[16][17];
    __shared__ float y3[416];
    __shared__ float y4[128];
    __shared__ float r2[128];
    int g = blockIdx.x, t = threadIdx.x;
    const float* fg = feat + (size_t)g * NPG * 128;

    for (int i = t; i < 2048; i += 256)
        wl1[(i >> 7) * 129 + (i & 127)] = c1w[i];
    if (t < NPG) vals[t] = fg[t * 128 + 127];
    __syncthreads();
    // stable descending rank (matches stable argsort(-v))
    if (t < NPG) {
        float v = vals[t];
        int r = 0;
        for (int j = 0; j < NPG; j++) {
            float u = vals[j];
            r += (u > v) || (u == v && j < t);
        }
        if (r < K_TOP) sel[r] = t;
    }
    __syncthreads();
    for (int i = t; i < K_TOP * 32; i += 256) {
        int k = i >> 5, c4 = i & 31;
        *(float4*)&tk[k * 132 + 4 * c4] = *(const float4*)&fg[sel[k] * 128 + 4 * c4];
    }
    __syncthreads();
    // conv1 (1x1), weights from LDS
    for (int i = t; i < 16 * K_TOP; i += 256) {
        int o = i & 15, k = i >> 4;
        float s = c1b[o];
        const float* wr = &wl1[o * 129];
        const float* xr = &tk[k * 132];
#pragma unroll 8
        for (int c = 0; c < 128; c++) s += wr[c] * xr[c];
        y1[o][k] = fmaxf(s, 0.f);
    }
    __syncthreads();
    // maxpool1d(2): 35 -> 17
    for (int i = t; i < 16 * 17; i += 256) {
        int o = i & 15, l = i >> 4;
        y2[o][l] = fmaxf(y1[o][2 * l], y1[o][2 * l + 1]);
    }
    __syncthreads();
    // conv2 (k=5, VALID): [16,17] -> [32,13]
    for (int idx = t; idx < 32 * 13; idx += 256) {
        int o2 = idx / 13, ttp = idx - o2 * 13;
        float s = c2b[o2];
        const float* wr = c2w + o2 * 80;
#pragma unroll
        for (int i = 0; i < 16; i++)
#pragma unroll
            for (int j = 0; j < 5; j++) s += wr[i * 5 + j] * y2[i][ttp + j];
        y3[idx] = fmaxf(s, 0.f);
    }
    __syncthreads();
    // fc1: 416 -> 128, 2 threads per output, float4 weight loads
    {
        int o = t >> 1, h = t & 1;
        const float4* wr4 = (const float4*)(f1w + o * 416) + h * 52;
        const float* yb = y3 + h * 208;
        float s = 0.f;
#pragma unroll 4
        for (int i = 0; i < 52; i++) {
            float4 w4 = wr4[i];
            s += w4.x * yb[4 * i] + w4.y * yb[4 * i + 1] +
                 w4.z * yb[4 * i + 2] + w4.w * yb[4 * i + 3];
        }
        s += __shfl_xor(s, 1);
        if (h == 0) y4[o] = fmaxf(s + f1b[o], 0.f);
    }
    __syncthreads();
    if (t < 128) r2[t] = f2w[t] * y4[t];
    __syncthreads();
    for (int off = 64; off > 0; off >>= 1) {
        if (t < off) r2[t] += r2[t + off];
        __syncthreads();
    }
    if (t == 0) out[g] = 1.0f / (1.0f + expf(-(r2[0] + f2b[0])));
}

// ---------------- launch ----------------

static inline size_t alignup(size_t x) { return (x + 255) & ~(size_t)255; }

extern "C" void kernel_launch(void* const* d_in, const int* in_sizes, int n_in,
                              void* d_out, int out_size, void* d_ws, size_t ws_size,
                              hipStream_t stream) {
    const float* x    = (const float*)d_in[0];
    const int*   ei   = (const int*)d_in[1];
    const int*   srcp = ei;
    const int*   dstp = ei + N_EDGES;
    const float* w0 = (const float*)d_in[3];
    const float* b0 = (const float*)d_in[4];
    const float* w1 = (const float*)d_in[5];
    const float* b1 = (const float*)d_in[6];
    const float* w2 = (const float*)d_in[7];
    const float* b2 = (const float*)d_in[8];
    const float* w3 = (const float*)d_in[9];
    const float* b3 = (const float*)d_in[10];
    const float* c1w = (const float*)d_in[11];
    const float* c1b = (const float*)d_in[12];
    const float* c2w = (const float*)d_in[13];
    const float* c2b = (const float*)d_in[14];
    const float* f1w = (const float*)d_in[15];
    const float* f1b = (const float*)d_in[16];
    const float* f2w = (const float*)d_in[17];
    const float* f2b = (const float*)d_in[18];
    float* out = (float*)d_out;

    char* p = (char*)d_ws;
    int* cnt     = (int*)p; p += alignup(sizeof(int) * N_NODES);
    int* row_ptr = (int*)p; p += alignup(sizeof(int) * N_NODES);
    float* dis   = (float*)p; p += alignup(sizeof(float) * N_NODES);
    int* bcnt    = (int*)p; p += alignup(sizeof(int) * NBUCK);
    int* csr     = (int*)p; p += alignup(sizeof(int) * (size_t)NBUCK * CAP);
    // union region: bdata (dead after k_build) aliases the two fp16 hs buffers
    char* U = p;
    unsigned int* bdata = (unsigned int*)U;
    char* hsA = U;                                        // 6.4 MB fp16
    char* hsB = U + alignup((size_t)N_NODES * 64);        // 6.4 MB fp16
    size_t usz = alignup(sizeof(unsigned int) * (size_t)NBUCK * CAP); // 13.65 MB
    float* feat = (float*)(U + usz);

    const int NB_M = (N_NODES + 511) / 512;        // 196 (2 nodes/thread)
    const int NB_A = (N_NODES * 32) / 256;         // 12500 (exact)

    hipMemsetAsync(bcnt, 0, sizeof(int) * NBUCK, stream);
    k_bin<<<NBB, 256, 0, stream>>>(srcp, dstp, bcnt, bdata);
    k_build<<<NBUCK, 1024, 0, stream>>>(bdata, bcnt, cnt, row_ptr, dis, csr);

    k_mm0<<<NB_M, 256, 0, stream>>>(x, w0, dis, hsA);
    k_agg<<<NB_A, 256, 0, stream>>>((const float4*)hsA, dis, row_ptr, cnt, csr, b0,
                                    feat, 0, w1, hsB);
    k_agg<<<NB_A, 256, 0, stream>>>((const float4*)hsB, dis, row_ptr, cnt, csr, b1,
                                    feat, 32, w2, hsA);
    k_agg<<<NB_A, 256, 0, stream>>>((const float4*)hsA, dis, row_ptr, cnt, csr, b2,
                                    feat, 64, w3, hsB);
    k_agg<<<NB_A, 256, 0, stream>>>((const float4*)hsB, dis, row_ptr, cnt, csr, b3,
                                    feat, 96, (const float*)nullptr, (char*)nullptr);

    k_head<<<N_GRAPHS, 256, 0, stream>>>(feat, c1w, c1b, c2w, c2b,
                                         f1w, f1b, f2w, f2b, out);
}

// Round 12
// 418.304 us; speedup vs baseline: 1.3538x; 1.1686x over previous
//
#include <hip/hip_runtime.h>
#include <hip/hip_fp16.h>
#include <math.h>

#define N_NODES 100000
#define N_EDGES 3200000
#define HIDDEN 32
#define K_TOP 35
#define NPG 100
#define N_GRAPHS 1000

#define BSHIFT 9
#define NLOC 512                    // nodes per bucket
#define NBUCK 196                   // ceil(100000/512)
#define CAP 17408                   // per-bucket capacity: mean 16384 + 8 sigma
#define NBB 1024                    // bin blocks
#define BIN_CHUNK 13                // 1024*256*13 >= 3.2M

typedef float vfloat4 __attribute__((ext_vector_type(4)));  // native vec for nontemporal

// ---------------- CSR build: single-pass binning into padded buckets ----------------

__global__ void k_bin(const int* __restrict__ src, const int* __restrict__ dst,
                      int* __restrict__ bcnt, unsigned int* __restrict__ bdata) {
    __shared__ int h[NBUCK];
    __shared__ int lbase[NBUCK];
    __shared__ int lcur[NBUCK];
    int t = threadIdx.x;
    for (int i = t; i < NBUCK; i += 256) { h[i] = 0; lcur[i] = 0; }
    __syncthreads();
    int base = blockIdx.x * (256 * BIN_CHUNK);
    int ss[BIN_CHUNK], ds[BIN_CHUNK];
#pragma unroll
    for (int k = 0; k < BIN_CHUNK; k++) {
        int e = base + k * 256 + t;
        if (e < N_EDGES) {
            ss[k] = src[e];
            ds[k] = dst[e];
            atomicAdd(&h[ds[k] >> BSHIFT], 1);
        } else ds[k] = -1;
    }
    __syncthreads();
    for (int i = t; i < NBUCK; i += 256)
        lbase[i] = h[i] ? atomicAdd(&bcnt[i], h[i]) : 0;
    __syncthreads();
#pragma unroll
    for (int k = 0; k < BIN_CHUNK; k++) {
        int d = ds[k];
        if (d >= 0) {
            int bk = d >> BSHIFT;
            int pos = atomicAdd(&lcur[bk], 1);
            bdata[bk * CAP + lbase[bk] + pos] =
                ((unsigned int)ss[k] << BSHIFT) | (unsigned int)(d & (NLOC - 1));
        }
    }
}

// merged: per-bucket counts + within-bucket scan -> cnt/row_ptr/dis, then CSR fill.
__global__ void k_build(const unsigned int* __restrict__ bdata, const int* __restrict__ bcnt,
                        int* __restrict__ cnt, int* __restrict__ row_ptr,
                        float* __restrict__ dis, int* __restrict__ csr) {
    __shared__ int h[NLOC];
    __shared__ int sd[NLOC];
    __shared__ int rp[NLOC];
    __shared__ int cur[NLOC];
    int b = blockIdx.x, t = threadIdx.x;   // 1024 threads
    if (t < NLOC) h[t] = 0;
    __syncthreads();
    int r0 = b * CAP, r1 = r0 + bcnt[b];
    for (int i = r0 + t; i < r1; i += 1024)
        atomicAdd(&h[bdata[i] & (NLOC - 1)], 1);
    __syncthreads();
    int v = (t < NLOC) ? h[t] : 0;
    if (t < NLOC) sd[t] = v;
    __syncthreads();
    for (int off = 1; off < NLOC; off <<= 1) {
        int x = (t >= off && t < NLOC) ? sd[t - off] : 0;
        __syncthreads();
        if (t < NLOC) sd[t] += x;
        __syncthreads();
    }
    if (t < NLOC) {
        int excl = sd[t] - v;
        int node = (b << BSHIFT) + t;
        rp[t] = r0 + excl;
        cur[t] = 0;
        if (node < N_NODES) {
            cnt[node] = v;
            dis[node] = rsqrtf((float)(v + 1));
            row_ptr[node] = r0 + excl;
        }
    }
    __syncthreads();
    for (int i = r0 + t; i < r1; i += 1024) {
        unsigned int u = bdata[i];
        int loc = u & (NLOC - 1);
        int pos = atomicAdd(&cur[loc], 1);
        csr[rp[loc] + pos] = (int)(u >> BSHIFT);
    }
}

// ---------------- GCN layer ----------------

// layer 0: hs[n] (fp16, 64B row) = dis[n] * (x @ w0); 2 nodes/thread halves LDS traffic
__global__ void k_mm0(const float* __restrict__ in, const float* __restrict__ w,
                      const float* __restrict__ dis, char* __restrict__ hs) {
    __shared__ float wl[128 * HIDDEN];
    int t = threadIdx.x;
    for (int i = t; i < 128 * HIDDEN; i += 256) wl[i] = w[i];
    __syncthreads();
    int n0 = blockIdx.x * 512 + t;
    int n1 = n0 + 256;
    bool has0 = n0 < N_NODES, has1 = n1 < N_NODES;
    int m0 = has0 ? n0 : 0, m1 = has1 ? n1 : 0;
    const float* r0p = in + (size_t)m0 * 128;
    const float* r1p = in + (size_t)m1 * 128;
    float acc0[HIDDEN], acc1[HIDDEN];
#pragma unroll
    for (int o = 0; o < HIDDEN; o++) { acc0[o] = 0.f; acc1[o] = 0.f; }
    for (int c4 = 0; c4 < 32; c4++) {
        float4 va = *(const float4*)(r0p + c4 * 4);
        float4 vb = *(const float4*)(r1p + c4 * 4);
        float xa[4] = {va.x, va.y, va.z, va.w};
        float xb[4] = {vb.x, vb.y, vb.z, vb.w};
#pragma unroll
        for (int k = 0; k < 4; k++) {
            const float* wr = &wl[(c4 * 4 + k) * HIDDEN];
#pragma unroll
            for (int o = 0; o < HIDDEN; o++) {
                float wv = wr[o];
                acc0[o] += xa[k] * wv;
                acc1[o] += xb[k] * wv;
            }
        }
    }
    if (has0) {
        float d = dis[m0];
        float4* hr = (float4*)(hs + (size_t)m0 * 64);
#pragma unroll
        for (int qq = 0; qq < 4; qq++) {
            __half2 p[4];
#pragma unroll
            for (int k = 0; k < 4; k++)
                p[k] = __floats2half2_rn(acc0[8 * qq + 2 * k] * d, acc0[8 * qq + 2 * k + 1] * d);
            hr[qq] = *(float4*)p;
        }
    }
    if (has1) {
        float d = dis[m1];
        float4* hr = (float4*)(hs + (size_t)m1 * 64);
#pragma unroll
        for (int qq = 0; qq < 4; qq++) {
            __half2 p[4];
#pragma unroll
            for (int k = 0; k < 4; k++)
                p[k] = __floats2half2_rn(acc1[8 * qq + 2 * k] * d, acc1[8 * qq + 2 * k + 1] * d);
            hr[qq] = *(float4*)p;
        }
    }
}

// fused: aggregate (fp16 gather, chunk-shuffle, fp32 accumulate) + DISTRIBUTED tanh
// epilogue (1 tanh/lane) + coalesced scalar feat write + next-layer matvec (LDS tv).
// half-wave per node; lane c: r=c&3 (16B quad), ph=c>>2 (edge phase / channel-in-quad).
__global__ void k_agg(const float4* __restrict__ hs4, const float* __restrict__ dis,
                      const int* __restrict__ row_ptr, const int* __restrict__ cnt,
                      const int* __restrict__ csr_src, const float* __restrict__ bias,
                      float* __restrict__ feat, int col_off,
                      const float* __restrict__ wnext, char* __restrict__ hsn) {
    __shared__ float wl[32 * 33];
    __shared__ float tv[8][36];
    int tt = threadIdx.x;
    if (wnext) {
        for (int i = tt; i < 1024; i += 256)
            wl[(i >> 5) * 33 + (i & 31)] = wnext[i];
    }
    __syncthreads();
    int n = (blockIdx.x * 256 + tt) >> 5;   // grid covers exactly N_NODES*32 lanes
    int c = tt & 31;
    int r = c & 3;       // 16B quad within 64B row
    int ph = c >> 2;     // edge phase (0..7) == channel within quad
    int slot = tt >> 5;
    int start = row_ptr[n];
    int m = cnt[n];
    float d = dis[n];
    float aA[8] = {0, 0, 0, 0, 0, 0, 0, 0};
    float aB[8] = {0, 0, 0, 0, 0, 0, 0, 0};

    for (int base = 0; base < m; base += 32) {
        int e = base + c;
        int idx = (e < m) ? csr_src[start + e] : 0;
        int id0 = __shfl(idx, ph, 32);
        int id1 = __shfl(idx, 8 + ph, 32);
        int id2 = __shfl(idx, 16 + ph, 32);
        int id3 = __shfl(idx, 24 + ph, 32);
        bool v0 = base + ph < m;
        bool v1 = base + 8 + ph < m;
        bool v2 = base + 16 + ph < m;
        bool v3 = base + 24 + ph < m;
        float4 g0 = hs4[(size_t)(v0 ? id0 : n) * 4 + r];
        float4 g1 = hs4[(size_t)(v1 ? id1 : n) * 4 + r];
        float4 g2 = hs4[(size_t)(v2 ? id2 : n) * 4 + r];
        float4 g3 = hs4[(size_t)(v3 ? id3 : n) * 4 + r];
        const __half2* h0 = (const __half2*)&g0;
        const __half2* h1 = (const __half2*)&g1;
        const __half2* h2 = (const __half2*)&g2;
        const __half2* h3 = (const __half2*)&g3;
        float2 f;
        if (v0) {
            f = __half22float2(h0[0]); aA[0] += f.x; aA[1] += f.y;
            f = __half22float2(h0[1]); aA[2] += f.x; aA[3] += f.y;
            f = __half22float2(h0[2]); aA[4] += f.x; aA[5] += f.y;
            f = __half22float2(h0[3]); aA[6] += f.x; aA[7] += f.y;
        }
        if (v1) {
            f = __half22float2(h1[0]); aB[0] += f.x; aB[1] += f.y;
            f = __half22float2(h1[1]); aB[2] += f.x; aB[3] += f.y;
            f = __half22float2(h1[2]); aB[4] += f.x; aB[5] += f.y;
            f = __half22float2(h1[3]); aB[6] += f.x; aB[7] += f.y;
        }
        if (v2) {
            f = __half22float2(h2[0]); aA[0] += f.x; aA[1] += f.y;
            f = __half22float2(h2[1]); aA[2] += f.x; aA[3] += f.y;
            f = __half22float2(h2[2]); aA[4] += f.x; aA[5] += f.y;
            f = __half22float2(h2[3]); aA[6] += f.x; aA[7] += f.y;
        }
        if (v3) {
            f = __half22float2(h3[0]); aB[0] += f.x; aB[1] += f.y;
            f = __half22float2(h3[1]); aB[2] += f.x; aB[3] += f.y;
            f = __half22float2(h3[2]); aB[4] += f.x; aB[5] += f.y;
            f = __half22float2(h3[3]); aB[6] += f.x; aB[7] += f.y;
        }
    }
    float s[8];
#pragma unroll
    for (int k = 0; k < 8; k++) {
        float v = aA[k] + aB[k];
        v += __shfl_xor(v, 4);
        v += __shfl_xor(v, 8);
        v += __shfl_xor(v, 16);
        s[k] = v;   // every lane: full sums for channels 8r..8r+7
    }
    // ---- distributed epilogue: lane c handles channel ch = 8r+ph ----
    // select s[ph] (dynamic -> cndmask tree)
    float s01 = (ph & 1) ? s[1] : s[0];
    float s23 = (ph & 1) ? s[3] : s[2];
    float s45 = (ph & 1) ? s[5] : s[4];
    float s67 = (ph & 1) ? s[7] : s[6];
    float s03 = (ph & 2) ? s23 : s01;
    float s47 = (ph & 2) ? s67 : s45;
    float sp  = (ph & 4) ? s47 : s03;
    // self term: element ph of the node's quad r
    float4 sv = hs4[(size_t)n * 4 + r];
    const __half2* sh = (const __half2*)&sv;
    __half2 q01 = (ph & 2) ? sh[1] : sh[0];
    __half2 q23 = (ph & 2) ? sh[3] : sh[2];
    __half2 qq  = (ph & 4) ? q23 : q01;
    float self = (ph & 1) ? __high2float(qq) : __low2float(qq);
    float bv = bias[8 * r + ph];
    float ov = tanhf(d * (sp + self) + bv);
    __builtin_nontemporal_store(ov, &feat[(size_t)n * 128 + col_off + 8 * r + ph]);
    if (wnext) {
        tv[slot][8 * r + ph] = ov;   // bijective index: conflict-free
        __builtin_amdgcn_wave_barrier();   // tv writes before reads (same wave)
        float o = 0.f;
#pragma unroll 8
        for (int k = 0; k < 32; k++)
            o += tv[slot][k] * wl[k * 33 + c];
        o *= d;
        float oh = __shfl_xor(o, 1);
        if ((c & 1) == 0) {
            __half2 pck = __floats2half2_rn(o, oh);
            *(__half2*)(hsn + (size_t)n * 64 + (size_t)c * 2) = pck;
        }
    }
}

// ---------------- sort-pool + head (one block per graph) ----------------

__global__ void __launch_bounds__(256, 4)
k_head(const float* __restrict__ feat,
       const float* __restrict__ c1w, const float* __restrict__ c1b,
       const float* __restrict__ c2w, const float* __restrict__ c2b,
       const float* __restrict__ f1w, const float* __restrict__ f1b,
       const float* __restrict__ f2w, const float* __restrict__ f2b,
       float* __restrict__ out) {
    __shared__ float vals[NPG];
    __shared__ int sel[K_TOP];
    __shared__ float tk[K_TOP * 132];
    __shared__ float wl1[16 * 129];
    __shared__ float y1[16][36];
    __shared__ float y2[16][17];
    __shared__ float y3[416];
    __shared__ float y4[128];
    __shared__ float r2[128];
    int g = blockIdx.x, t = threadIdx.x;
    const float* fg = feat + (size_t)g * NPG * 128;

    for (int i = t; i < 2048; i += 256)
        wl1[(i >> 7) * 129 + (i & 127)] = c1w[i];
    if (t < NPG) vals[t] = fg[t * 128 + 127];
    __syncthreads();
    // stable descending rank (matches stable argsort(-v))
    if (t < NPG) {
        float v = vals[t];
        int r = 0;
        for (int j = 0; j < NPG; j++) {
            float u = vals[j];
            r += (u > v) || (u == v && j < t);
        }
        if (r < K_TOP) sel[r] = t;
    }
    __syncthreads();
    for (int i = t; i < K_TOP * 32; i += 256) {
        int k = i >> 5, c4 = i & 31;
        *(float4*)&tk[k * 132 + 4 * c4] = *(const float4*)&fg[sel[k] * 128 + 4 * c4];
    }
    __syncthreads();
    // conv1 (1x1), weights from LDS
    for (int i = t; i < 16 * K_TOP; i += 256) {
        int o = i & 15, k = i >> 4;
        float s = c1b[o];
        const float* wr = &wl1[o * 129];
        const float* xr = &tk[k * 132];
#pragma unroll 8
        for (int c = 0; c < 128; c++) s += wr[c] * xr[c];
        y1[o][k] = fmaxf(s, 0.f);
    }
    __syncthreads();
    // maxpool1d(2): 35 -> 17
    for (int i = t; i < 16 * 17; i += 256) {
        int o = i & 15, l = i >> 4;
        y2[o][l] = fmaxf(y1[o][2 * l], y1[o][2 * l + 1]);
    }
    __syncthreads();
    // conv2 (k=5, VALID): [16,17] -> [32,13]
    for (int idx = t; idx < 32 * 13; idx += 256) {
        int o2 = idx / 13, ttp = idx - o2 * 13;
        float s = c2b[o2];
        const float* wr = c2w + o2 * 80;
#pragma unroll
        for (int i = 0; i < 16; i++)
#pragma unroll
            for (int j = 0; j < 5; j++) s += wr[i * 5 + j] * y2[i][ttp + j];
        y3[idx] = fmaxf(s, 0.f);
    }
    __syncthreads();
    // fc1: 416 -> 128, 2 threads per output, float4 weight loads
    {
        int o = t >> 1, h = t & 1;
        const float4* wr4 = (const float4*)(f1w + o * 416) + h * 52;
        const float* yb = y3 + h * 208;
        float s = 0.f;
#pragma unroll 4
        for (int i = 0; i < 52; i++) {
            float4 w4 = wr4[i];
            s += w4.x * yb[4 * i] + w4.y * yb[4 * i + 1] +
                 w4.z * yb[4 * i + 2] + w4.w * yb[4 * i + 3];
        }
        s += __shfl_xor(s, 1);
        if (h == 0) y4[o] = fmaxf(s + f1b[o], 0.f);
    }
    __syncthreads();
    if (t < 128) r2[t] = f2w[t] * y4[t];
    __syncthreads();
    for (int off = 64; off > 0; off >>= 1) {
        if (t < off) r2[t] += r2[t + off];
        __syncthreads();
    }
    if (t == 0) out[g] = 1.0f / (1.0f + expf(-(r2[0] + f2b[0])));
}

// ---------------- launch ----------------

static inline size_t alignup(size_t x) { return (x + 255) & ~(size_t)255; }

extern "C" void kernel_launch(void* const* d_in, const int* in_sizes, int n_in,
                              void* d_out, int out_size, void* d_ws, size_t ws_size,
                              hipStream_t stream) {
    const float* x    = (const float*)d_in[0];
    const int*   ei   = (const int*)d_in[1];
    const int*   srcp = ei;
    const int*   dstp = ei + N_EDGES;
    const float* w0 = (const float*)d_in[3];
    const float* b0 = (const float*)d_in[4];
    const float* w1 = (const float*)d_in[5];
    const float* b1 = (const float*)d_in[6];
    const float* w2 = (const float*)d_in[7];
    const float* b2 = (const float*)d_in[8];
    const float* w3 = (const float*)d_in[9];
    const float* b3 = (const float*)d_in[10];
    const float* c1w = (const float*)d_in[11];
    const float* c1b = (const float*)d_in[12];
    const float* c2w = (const float*)d_in[13];
    const float* c2b = (const float*)d_in[14];
    const float* f1w = (const float*)d_in[15];
    const float* f1b = (const float*)d_in[16];
    const float* f2w = (const float*)d_in[17];
    const float* f2b = (const float*)d_in[18];
    float* out = (float*)d_out;

    char* p = (char*)d_ws;
    int* cnt     = (int*)p; p += alignup(sizeof(int) * N_NODES);
    int* row_ptr = (int*)p; p += alignup(sizeof(int) * N_NODES);
    float* dis   = (float*)p; p += alignup(sizeof(float) * N_NODES);
    int* bcnt    = (int*)p; p += alignup(sizeof(int) * NBUCK);
    int* csr     = (int*)p; p += alignup(sizeof(int) * (size_t)NBUCK * CAP);
    // union region: bdata (dead after k_build) aliases the two fp16 hs buffers
    char* U = p;
    unsigned int* bdata = (unsigned int*)U;
    char* hsA = U;                                        // 6.4 MB fp16
    char* hsB = U + alignup((size_t)N_NODES * 64);        // 6.4 MB fp16
    size_t usz = alignup(sizeof(unsigned int) * (size_t)NBUCK * CAP); // 13.65 MB
    float* feat = (float*)(U + usz);

    const int NB_M = (N_NODES + 511) / 512;        // 196 (2 nodes/thread)
    const int NB_A = (N_NODES * 32) / 256;         // 12500 (exact)

    hipMemsetAsync(bcnt, 0, sizeof(int) * NBUCK, stream);
    k_bin<<<NBB, 256, 0, stream>>>(srcp, dstp, bcnt, bdata);
    k_build<<<NBUCK, 1024, 0, stream>>>(bdata, bcnt, cnt, row_ptr, dis, csr);

    k_mm0<<<NB_M, 256, 0, stream>>>(x, w0, dis, hsA);
    k_agg<<<NB_A, 256, 0, stream>>>((const float4*)hsA, dis, row_ptr, cnt, csr, b0,
                                    feat, 0, w1, hsB);
    k_agg<<<NB_A, 256, 0, stream>>>((const float4*)hsB, dis, row_ptr, cnt, csr, b1,
                                    feat, 32, w2, hsA);
    k_agg<<<NB_A, 256, 0, stream>>>((const float4*)hsA, dis, row_ptr, cnt, csr, b2,
                                    feat, 64, w3, hsB);
    k_agg<<<NB_A, 256, 0, stream>>>((const float4*)hsB, dis, row_ptr, cnt, csr, b3,
                                    feat, 96, (const float*)nullptr, (char*)nullptr);

    k_head<<<N_GRAPHS, 256, 0, stream>>>(feat, c1w, c1b, c2w, c2b,
                                         f1w, f1b, f2w, f2b, out);
}